// Round 1
// baseline (1849.800 us; speedup 1.0000x reference)
//
#include <hip/hip_runtime.h>
#include <math.h>

// MultipleTopoTreeLoss: sum over MST edges of squared edge length, per
// (chunk, sample), averaged.  r: [16, 2048, 3] f32, split into 2 chunks of
// 1024 points along axis 1, per-sample per-channel standardized, then
// Prim's MST on squared Euclidean distances.  Output: scalar f32.
//
// One wave (64 lanes) per (sample, chunk) pair -> 32 blocks.  Each lane owns
// 16 points held in registers; mind[] also in registers (statically indexed,
// fully unrolled).  Visited marker: mind == INF.  Per Prim step, the
// distance-update and the next argmin are fused into one sweep, then a
// 6-step __shfl_xor butterfly reduces (min, idx) across the wave with
// index tie-breaking (all lanes converge to identical result).

#define NPTS   1024   // points per chunk-sample
#define EPK    16     // elements per lane (1024 / 64)
#define NSAMP  16
#define NCHUNK 2

__device__ __forceinline__ float wave_sum(float v) {
#pragma unroll
  for (int off = 32; off > 0; off >>= 1) v += __shfl_xor(v, off, 64);
  return v;
}

__device__ __forceinline__ void wave_argmin(float& m, int& i) {
#pragma unroll
  for (int off = 32; off > 0; off >>= 1) {
    float om = __shfl_xor(m, off, 64);
    int   oi = __shfl_xor(i, off, 64);
    if (om < m || (om == m && oi < i)) { m = om; i = oi; }
  }
}

__global__ __launch_bounds__(64) void mst_prim_kernel(
    const float* __restrict__ r, float* __restrict__ out) {
  const int blk  = blockIdx.x;   // 0..31
  const int b    = blk >> 1;     // sample 0..15
  const int c    = blk & 1;      // chunk 0..1
  const int lane = threadIdx.x;  // 0..63

  __shared__ float4 pts[NPTS];   // normalized points, .w = 0 (16 KiB)

  const float* __restrict__ base =
      r + (size_t)b * (NPTS * NCHUNK * 3) + (size_t)c * (NPTS * 3);

  // ---- load own 16 points (contiguous 48 floats per lane) ----
  float x[EPK], y[EPK], z[EPK];
#pragma unroll
  for (int k = 0; k < EPK; ++k) {
    const int i = lane * EPK + k;
    x[k] = base[i * 3 + 0];
    y[k] = base[i * 3 + 1];
    z[k] = base[i * 3 + 2];
  }

  // ---- per-channel mean ----
  float sx = 0.f, sy = 0.f, sz = 0.f;
#pragma unroll
  for (int k = 0; k < EPK; ++k) { sx += x[k]; sy += y[k]; sz += z[k]; }
  sx = wave_sum(sx); sy = wave_sum(sy); sz = wave_sum(sz);
  const float mx = sx * (1.f / NPTS);
  const float my = sy * (1.f / NPTS);
  const float mz = sz * (1.f / NPTS);

  // ---- per-channel std (biased, ddof=0), two-pass ----
  float vx = 0.f, vy = 0.f, vz = 0.f;
#pragma unroll
  for (int k = 0; k < EPK; ++k) {
    const float dx = x[k] - mx, dy = y[k] - my, dz = z[k] - mz;
    vx += dx * dx; vy += dy * dy; vz += dz * dz;
  }
  vx = wave_sum(vx); vy = wave_sum(vy); vz = wave_sum(vz);
  const float ix = 1.f / (sqrtf(vx * (1.f / NPTS)) + 1e-8f);
  const float iy = 1.f / (sqrtf(vy * (1.f / NPTS)) + 1e-8f);
  const float iz = 1.f / (sqrtf(vz * (1.f / NPTS)) + 1e-8f);

  // ---- normalize in-register, publish to LDS for broadcast lookups ----
#pragma unroll
  for (int k = 0; k < EPK; ++k) {
    x[k] = (x[k] - mx) * ix;
    y[k] = (y[k] - my) * iy;
    z[k] = (z[k] - mz) * iz;
    pts[lane * EPK + k] = make_float4(x[k], y[k], z[k], 0.f);
  }
  __syncthreads();

  // ---- Prim prologue: seed from node 0 ----
  float mind[EPK];
  const float4 q0 = pts[0];
  float lm = INFINITY; int li = 0x7fffffff;
#pragma unroll
  for (int k = 0; k < EPK; ++k) {
    const int i = lane * EPK + k;
    const float dx = x[k] - q0.x, dy = y[k] - q0.y, dz = z[k] - q0.z;
    float d2 = dx * dx + dy * dy + dz * dz;
    if (i == 0) d2 = INFINITY;  // node 0 is visited
    mind[k] = d2;
    if (d2 < lm) { lm = d2; li = i; }
  }
  wave_argmin(lm, li);
  float total = lm;   // first MST edge (squared length)
  int   j     = li;   // newly added node

  // ---- main loop: fused update + argmin, NPTS-2 more edges ----
  for (int t = 0; t < NPTS - 2; ++t) {
    const float4 q = pts[j];  // broadcast read (all lanes same address)
    lm = INFINITY; li = 0x7fffffff;
#pragma unroll
    for (int k = 0; k < EPK; ++k) {
      const int i = lane * EPK + k;
      float m = mind[k];
      if (i == j) {
        m = INFINITY;           // mark newly-added node visited
        mind[k] = m;
      } else if (m < INFINITY) { // unvisited: relax against new node
        const float dx = x[k] - q.x, dy = y[k] - q.y, dz = z[k] - q.z;
        const float d2 = dx * dx + dy * dy + dz * dz;
        m = fminf(m, d2);
        mind[k] = m;
      }
      if (m < lm) { lm = m; li = i; }
    }
    wave_argmin(lm, li);
    total += lm;
    j = li;
  }

  // ---- accumulate: mean over 16 samples per chunk, then /2 chunks ----
  if (lane == 0) {
    atomicAdd(out, total * (1.0f / (NSAMP * NCHUNK)));
  }
}

extern "C" void kernel_launch(void* const* d_in, const int* in_sizes, int n_in,
                              void* d_out, int out_size, void* d_ws, size_t ws_size,
                              hipStream_t stream) {
  const float* r = (const float*)d_in[0];
  float* out = (float*)d_out;
  (void)in_sizes; (void)n_in; (void)d_ws; (void)ws_size;

  // d_out is poisoned with 0xAA before every call — zero it (async, capturable)
  hipMemsetAsync(out, 0, out_size * sizeof(float), stream);

  mst_prim_kernel<<<dim3(NSAMP * NCHUNK), dim3(64), 0, stream>>>(r, out);
}

// Round 2
// 233.954 us; speedup vs baseline: 7.9067x; 7.9067x over previous
//
#include <hip/hip_runtime.h>
#include <math.h>
#include <stdint.h>

// MultipleTopoTreeLoss = mean over 32 (sample,chunk) pairs of sum of squared
// Euclidean-MST edge lengths of 1024 standardized 3-D points.
//
// Round-1 post-mortem: Prim is a 1022-step serial latency chain (VALUBusy
// 1.6%, 4200 cy/step).  Switch to Boruvka: <=10 fully-parallel rounds.
//   Round = A) every node finds its nearest node in a different component
//              (full 1024-candidate scan, LDS-broadcast reads), per-component
//              min via atomicMin on u64 key = (d2bits<<32 | min(i,j)<<10 | max)
//              -- symmetric key => total order on edges => hooking graph has
//              only 2-cycles, dedupe by full key equality.
//           B) per sample (1 block): hook parent[c]=c2, add weight once per
//              unique edge, break 2-cycles, pointer-chase to roots, relabel,
//              count components, early-exit flag.
// Random data converges in ~6 rounds; dead rounds cost ~2us (flag exit).

#define NSAMP   32      // 16 batch x 2 chunks
#define NPTS    1024
#define BPS     8       // scan blocks per sample
#define NPB     128     // nodes per scan block (BPS*NPB = NPTS)
#define ROUNDS  10
#define EMPTY64 0xFFFFFFFFFFFFFFFFull

__device__ __forceinline__ float block_sum(float v, volatile float* red) {
#pragma unroll
  for (int off = 32; off > 0; off >>= 1) v += __shfl_xor(v, off, 64);
  __syncthreads();                       // protect red reuse across calls
  if ((threadIdx.x & 63) == 0) red[threadIdx.x >> 6] = v;
  __syncthreads();
  return red[0] + red[1] + red[2] + red[3];
}

// ---- Phase 0: standardize points, init state -------------------------------
__global__ __launch_bounds__(256) void norm_init_kernel(
    const float* __restrict__ r, float4* __restrict__ pts4,
    unsigned long long* __restrict__ winner, int* __restrict__ comp,
    int* __restrict__ ncomp, float* __restrict__ totals) {
  const int s = blockIdx.x;             // 0..31
  const int b = s >> 1, c = s & 1;
  const int tid = threadIdx.x;
  const float* __restrict__ base = r + ((size_t)b * 2 + c) * (NPTS * 3);
  __shared__ float red[4];

  float x[4], y[4], z[4];
  float sx = 0.f, sy = 0.f, sz = 0.f;
#pragma unroll
  for (int k = 0; k < 4; ++k) {
    const int i = k * 256 + tid;
    x[k] = base[i * 3 + 0]; y[k] = base[i * 3 + 1]; z[k] = base[i * 3 + 2];
    sx += x[k]; sy += y[k]; sz += z[k];
  }
  sx = block_sum(sx, red); sy = block_sum(sy, red); sz = block_sum(sz, red);
  const float mx = sx * (1.f / NPTS), my = sy * (1.f / NPTS), mz = sz * (1.f / NPTS);

  float vx = 0.f, vy = 0.f, vz = 0.f;
#pragma unroll
  for (int k = 0; k < 4; ++k) {
    const float dx = x[k] - mx, dy = y[k] - my, dz = z[k] - mz;
    vx += dx * dx; vy += dy * dy; vz += dz * dz;
  }
  vx = block_sum(vx, red); vy = block_sum(vy, red); vz = block_sum(vz, red);
  const float ix = 1.f / (sqrtf(vx * (1.f / NPTS)) + 1e-8f);
  const float iy = 1.f / (sqrtf(vy * (1.f / NPTS)) + 1e-8f);
  const float iz = 1.f / (sqrtf(vz * (1.f / NPTS)) + 1e-8f);

#pragma unroll
  for (int k = 0; k < 4; ++k) {
    const int i = k * 256 + tid;
    pts4[s * NPTS + i] =
        make_float4((x[k] - mx) * ix, (y[k] - my) * iy, (z[k] - mz) * iz, 0.f);
    comp[s * NPTS + i] = i;
    winner[s * NPTS + i] = EMPTY64;
  }
  if (tid == 0) { ncomp[s] = NPTS; totals[s] = 0.f; }
}

// ---- Phase A: per-node nearest-other-component, per-component atomicMin ----
__global__ __launch_bounds__(256) void scan_kernel(
    const float4* __restrict__ pts4, const int* __restrict__ comp,
    unsigned long long* __restrict__ winner, const int* __restrict__ ncomp) {
  const int blk = blockIdx.x;
  const int s = blk >> 3;               // /BPS
  const int part = blk & 7;             // %BPS
  if (ncomp[s] == 1) return;            // sample finished: dead round

  __shared__ float4 P[NPTS];            // 16 KiB, .w = comp bits
  const int tid = threadIdx.x;
  const float4* __restrict__ sp = pts4 + s * NPTS;
  const int* __restrict__ sc = comp + s * NPTS;
#pragma unroll
  for (int k = 0; k < 4; ++k) {
    const int i = k * 256 + tid;
    float4 p = sp[i];
    p.w = __uint_as_float((unsigned)sc[i]);
    P[i] = p;
  }
  __syncthreads();

  const int node = part * NPB + (tid & (NPB - 1));
  const int half = tid >> 7;            // 2 threads split the candidate range
  const float4 me = P[node];
  const unsigned mycomp = __float_as_uint(me.w);

  float dbest = INFINITY; int jbest = node;
  const int j0 = half * (NPTS / 2);
#pragma unroll 8
  for (int jj = 0; jj < NPTS / 2; ++jj) {
    const int j = j0 + jj;
    const float4 q = P[j];              // same addr across wave: broadcast
    const float dx = me.x - q.x, dy = me.y - q.y, dz = me.z - q.z;
    float d2 = dx * dx + dy * dy + dz * dz;
    d2 = (__float_as_uint(q.w) == mycomp) ? INFINITY : d2;
    if (d2 < dbest) { dbest = d2; jbest = j; }
  }
  if (dbest < INFINITY) {
    const unsigned a = (unsigned)(node < jbest ? node : jbest);
    const unsigned b = (unsigned)(node < jbest ? jbest : node);
    const unsigned long long key =
        ((unsigned long long)__float_as_uint(dbest) << 32) | (a << 10) | b;
    atomicMin(&winner[s * NPTS + mycomp], key);
  }
}

// ---- Phase B: hook, dedupe-add, contract, relabel --------------------------
__global__ __launch_bounds__(256) void combine_kernel(
    unsigned long long* __restrict__ winner, int* __restrict__ comp,
    int* __restrict__ ncomp, float* __restrict__ totals) {
  const int s = blockIdx.x;
  if (ncomp[s] == 1) return;

  __shared__ unsigned long long W[NPTS];  // 8 KiB
  __shared__ short compOld[NPTS];         // 2 KiB
  __shared__ short parentL[NPTS];         // 2 KiB
  __shared__ short rootL[NPTS];           // 2 KiB
  __shared__ float red[4];
  const int tid = threadIdx.x;
  unsigned long long* __restrict__ gw = winner + s * NPTS;
  int* __restrict__ gcomp = comp + s * NPTS;

#pragma unroll
  for (int k = 0; k < 4; ++k) {
    const int i = k * 256 + tid;
    W[i] = gw[i];
    compOld[i] = (short)gcomp[i];
    gw[i] = EMPTY64;                    // clear for next round's scan
  }
  __syncthreads();

  float wsum = 0.f;
#pragma unroll
  for (int k = 0; k < 4; ++k) {
    const int c = k * 256 + tid;
    const unsigned long long w = W[c];
    short par = (short)c;
    if (w != EMPTY64) {
      const int pmin = (int)((w >> 10) & 1023u);
      const int pmax = (int)(w & 1023u);
      const int c2 = (compOld[pmin] == c) ? (int)compOld[pmax]
                                          : (int)compOld[pmin];
      par = (short)c2;
      // same undirected edge selected by both sides <=> identical u64 key
      const bool dup = (W[c2] == w);
      if (!dup || c < c2) wsum += __uint_as_float((unsigned)(w >> 32));
    }
    parentL[c] = par;
  }
  __syncthreads();
  // break 2-cycles: smaller index becomes root (benign race, see analysis)
#pragma unroll
  for (int k = 0; k < 4; ++k) {
    const int c = k * 256 + tid;
    const int p = parentL[c];
    if (p != c && parentL[p] == c && c < p) parentL[c] = (short)c;
  }
  __syncthreads();
  // chase to roots (forest after 2-cycle break; cap for tie-degeneracy safety)
#pragma unroll
  for (int k = 0; k < 4; ++k) {
    const int c = k * 256 + tid;
    int p = parentL[c];
    for (int it = 0; it < 2048 && parentL[p] != p; ++it) p = parentL[p];
    rootL[c] = (short)p;
  }
  __syncthreads();
  int cnt = 0;
#pragma unroll
  for (int k = 0; k < 4; ++k) {
    const int i = k * 256 + tid;
    const int nc = rootL[compOld[i]];
    gcomp[i] = nc;
    cnt += (nc == i);                   // comp id r always has comp[r]==r
  }
  const float tot = block_sum(wsum, red);
  const float fcnt = block_sum((float)cnt, red);
  if (tid == 0) { totals[s] += tot; ncomp[s] = (int)fcnt; }
}

// ---- Final reduction -------------------------------------------------------
__global__ __launch_bounds__(64) void finish_kernel(
    const float* __restrict__ totals, float* __restrict__ out) {
  float v = (threadIdx.x < NSAMP) ? totals[threadIdx.x] : 0.f;
#pragma unroll
  for (int off = 32; off > 0; off >>= 1) v += __shfl_xor(v, off, 64);
  if (threadIdx.x == 0) out[0] = v * (1.f / NSAMP);
}

extern "C" void kernel_launch(void* const* d_in, const int* in_sizes, int n_in,
                              void* d_out, int out_size, void* d_ws, size_t ws_size,
                              hipStream_t stream) {
  const float* r = (const float*)d_in[0];
  float* out = (float*)d_out;
  (void)in_sizes; (void)n_in; (void)out_size; (void)ws_size;

  char* ws = (char*)d_ws;               // ~0.9 MB used
  float4* pts4 = (float4*)ws;                                     // 512 KiB
  unsigned long long* winner = (unsigned long long*)(ws + 524288); // 256 KiB
  int* comp    = (int*)(ws + 786432);                             // 128 KiB
  int* ncomp   = (int*)(ws + 917504);
  float* totals = (float*)(ws + 917632);

  norm_init_kernel<<<dim3(NSAMP), dim3(256), 0, stream>>>(
      r, pts4, winner, comp, ncomp, totals);
  for (int rd = 0; rd < ROUNDS; ++rd) {
    scan_kernel<<<dim3(NSAMP * BPS), dim3(256), 0, stream>>>(
        pts4, comp, winner, ncomp);
    combine_kernel<<<dim3(NSAMP), dim3(256), 0, stream>>>(
        winner, comp, ncomp, totals);
  }
  finish_kernel<<<dim3(1), dim3(64), 0, stream>>>(totals, out);
}

// Round 3
// 159.305 us; speedup vs baseline: 11.6117x; 1.4686x over previous
//
#include <hip/hip_runtime.h>
#include <math.h>
#include <stdint.h>

// MultipleTopoTreeLoss = mean over 32 (sample,chunk) pairs of sum of squared
// Euclidean-MST edge lengths of 1024 standardized 3-D points.
//
// Boruvka, <=10 fully-parallel rounds (round-1 post-mortem: Prim's 1022-step
// serial chain was latency-bound at 1798us).  Round-2 post-mortem: scan was
// latency-bound at 1 wave/SIMD (occupancy 6.6%, 187 cy/iter vs ~22 issue).
// Round 3: 4 blocks/CU (1024 scan blocks), 2 independent min-chains for ILP,
// and LDS pre-reduction of per-component atomicMin before global flush.
//
//   scan:    node's nearest neighbor in a different component; per-component
//            min via u64 key = d2bits<<32 | min(i,j)<<10 | max(i,j).
//            Symmetric key => total edge order => hooking graph has only
//            2-cycles; dedupe by key equality.
//   combine: hook parent[c]=c2, add weight once per unique edge, break
//            2-cycles (smaller root wins), chase to roots, relabel, count.

#define NSAMP   32      // 16 batch x 2 chunks
#define NPTS    1024
#define BPS     32      // scan blocks per sample
#define NPB     32      // nodes per scan block
#define NSUB    8       // candidate subranges per node
#define CPT     128     // candidates per thread (NPTS / NSUB)
#define ROUNDS  10
#define EMPTY64 0xFFFFFFFFFFFFFFFFull

__device__ __forceinline__ float block_sum(float v, volatile float* red) {
#pragma unroll
  for (int off = 32; off > 0; off >>= 1) v += __shfl_xor(v, off, 64);
  __syncthreads();                       // protect red reuse across calls
  if ((threadIdx.x & 63) == 0) red[threadIdx.x >> 6] = v;
  __syncthreads();
  return red[0] + red[1] + red[2] + red[3];
}

// ---- Phase 0: standardize points, init state -------------------------------
__global__ __launch_bounds__(256) void norm_init_kernel(
    const float* __restrict__ r, float4* __restrict__ pts4,
    unsigned long long* __restrict__ winner, int* __restrict__ comp,
    int* __restrict__ ncomp, float* __restrict__ totals) {
  const int s = blockIdx.x;             // 0..31
  const int b = s >> 1, c = s & 1;
  const int tid = threadIdx.x;
  const float* __restrict__ base = r + ((size_t)b * 2 + c) * (NPTS * 3);
  __shared__ float red[4];

  float x[4], y[4], z[4];
  float sx = 0.f, sy = 0.f, sz = 0.f;
#pragma unroll
  for (int k = 0; k < 4; ++k) {
    const int i = k * 256 + tid;
    x[k] = base[i * 3 + 0]; y[k] = base[i * 3 + 1]; z[k] = base[i * 3 + 2];
    sx += x[k]; sy += y[k]; sz += z[k];
  }
  sx = block_sum(sx, red); sy = block_sum(sy, red); sz = block_sum(sz, red);
  const float mx = sx * (1.f / NPTS), my = sy * (1.f / NPTS), mz = sz * (1.f / NPTS);

  float vx = 0.f, vy = 0.f, vz = 0.f;
#pragma unroll
  for (int k = 0; k < 4; ++k) {
    const float dx = x[k] - mx, dy = y[k] - my, dz = z[k] - mz;
    vx += dx * dx; vy += dy * dy; vz += dz * dz;
  }
  vx = block_sum(vx, red); vy = block_sum(vy, red); vz = block_sum(vz, red);
  const float ix = 1.f / (sqrtf(vx * (1.f / NPTS)) + 1e-8f);
  const float iy = 1.f / (sqrtf(vy * (1.f / NPTS)) + 1e-8f);
  const float iz = 1.f / (sqrtf(vz * (1.f / NPTS)) + 1e-8f);

#pragma unroll
  for (int k = 0; k < 4; ++k) {
    const int i = k * 256 + tid;
    pts4[s * NPTS + i] =
        make_float4((x[k] - mx) * ix, (y[k] - my) * iy, (z[k] - mz) * iz, 0.f);
    comp[s * NPTS + i] = i;
    winner[s * NPTS + i] = EMPTY64;
  }
  if (tid == 0) { ncomp[s] = NPTS; totals[s] = 0.f; }
}

// ---- Phase A: nearest-other-component scan, LDS-pre-reduced atomicMin ------
__global__ __launch_bounds__(256) void scan_kernel(
    const float4* __restrict__ pts4, const int* __restrict__ comp,
    unsigned long long* __restrict__ winner, const int* __restrict__ ncomp) {
  const int blk = blockIdx.x;
  const int s = blk >> 5;               // / BPS
  const int part = blk & (BPS - 1);
  if (ncomp[s] == 1) return;            // sample finished: dead round

  __shared__ float4 P[NPTS];                     // 16 KiB, .w = comp bits
  __shared__ unsigned long long Wl[NPTS];        // 8 KiB, per-comp winner
  const int tid = threadIdx.x;
  const float4* __restrict__ sp = pts4 + s * NPTS;
  const int* __restrict__ sc = comp + s * NPTS;
#pragma unroll
  for (int k = 0; k < 4; ++k) {
    const int i = k * 256 + tid;
    float4 p = sp[i];
    p.w = __uint_as_float((unsigned)sc[i]);
    P[i] = p;
    Wl[i] = EMPTY64;
  }
  __syncthreads();

  const int node = part * NPB + (tid & (NPB - 1));
  const int sub  = tid >> 5;            // 8 subranges
  const float4 me = P[node];
  const unsigned mycomp = __float_as_uint(me.w);

  // two independent min-chains for ILP
  float d0 = INFINITY, d1 = INFINITY;
  int   j0 = node,     j1 = node;
  const int cbase = sub * CPT;
#pragma unroll 4
  for (int jj = 0; jj < CPT; jj += 2) {
    const float4 qa = P[cbase + jj];      // 2 broadcast addrs per wave: free
    const float4 qb = P[cbase + jj + 1];
    const float ax = me.x - qa.x, ay = me.y - qa.y, az = me.z - qa.z;
    const float bx = me.x - qb.x, by = me.y - qb.y, bz = me.z - qb.z;
    float da = ax * ax + ay * ay + az * az;
    float db = bx * bx + by * by + bz * bz;
    da = (__float_as_uint(qa.w) == mycomp) ? INFINITY : da;
    db = (__float_as_uint(qb.w) == mycomp) ? INFINITY : db;
    if (da < d0) { d0 = da; j0 = cbase + jj; }
    if (db < d1) { d1 = db; j1 = cbase + jj + 1; }
  }
  if (fminf(d0, d1) < INFINITY) {
    const unsigned a0 = (unsigned)(node < j0 ? node : j0);
    const unsigned b0 = (unsigned)(node < j0 ? j0 : node);
    const unsigned a1 = (unsigned)(node < j1 ? node : j1);
    const unsigned b1 = (unsigned)(node < j1 ? j1 : node);
    const unsigned long long k0 =
        ((unsigned long long)__float_as_uint(d0) << 32) | (a0 << 10) | b0;
    const unsigned long long k1 =
        ((unsigned long long)__float_as_uint(d1) << 32) | (a1 << 10) | b1;
    const unsigned long long key = k0 < k1 ? k0 : k1;
    atomicMin(&Wl[mycomp], key);        // LDS pre-reduction
  }
  __syncthreads();

  unsigned long long* __restrict__ gw = winner + s * NPTS;
#pragma unroll
  for (int k = 0; k < 4; ++k) {
    const int c2 = k * 256 + tid;
    const unsigned long long w = Wl[c2];
    if (w != EMPTY64) atomicMin(&gw[c2], w);   // <= NPB slots non-empty
  }
}

// ---- Phase B: hook, dedupe-add, contract, relabel --------------------------
__global__ __launch_bounds__(256) void combine_kernel(
    unsigned long long* __restrict__ winner, int* __restrict__ comp,
    int* __restrict__ ncomp, float* __restrict__ totals) {
  const int s = blockIdx.x;
  if (ncomp[s] == 1) return;

  __shared__ unsigned long long W[NPTS];  // 8 KiB
  __shared__ short compOld[NPTS];         // 2 KiB
  __shared__ short parentL[NPTS];         // 2 KiB
  __shared__ short rootL[NPTS];           // 2 KiB
  __shared__ float red[4];
  const int tid = threadIdx.x;
  unsigned long long* __restrict__ gw = winner + s * NPTS;
  int* __restrict__ gcomp = comp + s * NPTS;

#pragma unroll
  for (int k = 0; k < 4; ++k) {
    const int i = k * 256 + tid;
    W[i] = gw[i];
    compOld[i] = (short)gcomp[i];
    gw[i] = EMPTY64;                    // clear for next round's scan
  }
  __syncthreads();

  float wsum = 0.f;
#pragma unroll
  for (int k = 0; k < 4; ++k) {
    const int c = k * 256 + tid;
    const unsigned long long w = W[c];
    short par = (short)c;
    if (w != EMPTY64) {
      const int pmin = (int)((w >> 10) & 1023u);
      const int pmax = (int)(w & 1023u);
      const int c2 = (compOld[pmin] == c) ? (int)compOld[pmax]
                                          : (int)compOld[pmin];
      par = (short)c2;
      // same undirected edge selected by both sides <=> identical u64 key
      const bool dup = (W[c2] == w);
      if (!dup || c < c2) wsum += __uint_as_float((unsigned)(w >> 32));
    }
    parentL[c] = par;
  }
  __syncthreads();
  // break 2-cycles: smaller index becomes root
#pragma unroll
  for (int k = 0; k < 4; ++k) {
    const int c = k * 256 + tid;
    const int p = parentL[c];
    if (p != c && parentL[p] == c && c < p) parentL[c] = (short)c;
  }
  __syncthreads();
  // chase to roots (forest after 2-cycle break)
#pragma unroll
  for (int k = 0; k < 4; ++k) {
    const int c = k * 256 + tid;
    int p = parentL[c];
    for (int it = 0; it < 2048 && parentL[p] != p; ++it) p = parentL[p];
    rootL[c] = (short)p;
  }
  __syncthreads();
  int cnt = 0;
#pragma unroll
  for (int k = 0; k < 4; ++k) {
    const int i = k * 256 + tid;
    const int nc = rootL[compOld[i]];
    gcomp[i] = nc;
    cnt += (nc == i);                   // comp id r always has comp[r]==r
  }
  const float tot = block_sum(wsum, red);
  const float fcnt = block_sum((float)cnt, red);
  if (tid == 0) { totals[s] += tot; ncomp[s] = (int)fcnt; }
}

// ---- Final reduction -------------------------------------------------------
__global__ __launch_bounds__(64) void finish_kernel(
    const float* __restrict__ totals, float* __restrict__ out) {
  float v = (threadIdx.x < NSAMP) ? totals[threadIdx.x] : 0.f;
#pragma unroll
  for (int off = 32; off > 0; off >>= 1) v += __shfl_xor(v, off, 64);
  if (threadIdx.x == 0) out[0] = v * (1.f / NSAMP);
}

extern "C" void kernel_launch(void* const* d_in, const int* in_sizes, int n_in,
                              void* d_out, int out_size, void* d_ws, size_t ws_size,
                              hipStream_t stream) {
  const float* r = (const float*)d_in[0];
  float* out = (float*)d_out;
  (void)in_sizes; (void)n_in; (void)out_size; (void)ws_size;

  char* ws = (char*)d_ws;               // ~0.9 MB used
  float4* pts4 = (float4*)ws;                                      // 512 KiB
  unsigned long long* winner = (unsigned long long*)(ws + 524288); // 256 KiB
  int* comp    = (int*)(ws + 786432);                              // 128 KiB
  int* ncomp   = (int*)(ws + 917504);
  float* totals = (float*)(ws + 917632);

  norm_init_kernel<<<dim3(NSAMP), dim3(256), 0, stream>>>(
      r, pts4, winner, comp, ncomp, totals);
  for (int rd = 0; rd < ROUNDS; ++rd) {
    scan_kernel<<<dim3(NSAMP * BPS), dim3(256), 0, stream>>>(
        pts4, comp, winner, ncomp);
    combine_kernel<<<dim3(NSAMP), dim3(256), 0, stream>>>(
        winner, comp, ncomp, totals);
  }
  finish_kernel<<<dim3(1), dim3(64), 0, stream>>>(totals, out);
}